// Round 7
// baseline (872.570 us; speedup 1.0000x reference)
//
#include <hip/hip_runtime.h>
#include <hip/hip_bf16.h>
#include <math.h>

#define H 128
#define XS 300
#define NCLS 5
#define KPAD 320
#define NXCD 8

typedef __attribute__((ext_vector_type(8))) short short8;
typedef __attribute__((ext_vector_type(4))) float f32x4;

static __device__ inline unsigned short f2bf(float f) {
    __hip_bfloat16 h = __float2bfloat16(f);
    return *reinterpret_cast<unsigned short*>(&h);
}
static __device__ inline float bf2f(unsigned short u) {
    unsigned int x = ((unsigned int)u) << 16;
    return __builtin_bit_cast(float, x);
}
static __device__ inline float sigm(float v) { return 1.f / (1.f + __expf(-v)); }

// ---------------------------------------------------------------------------
// mask conversion with dtype auto-detect (bool-bytes vs int32)
// ---------------------------------------------------------------------------
__global__ void mask_conv_kernel(const void* __restrict__ mask_raw,
                                 float* __restrict__ m, int n) {
    const unsigned int* w = (const unsigned int*)mask_raw;
    bool is_bytes = false;
#pragma unroll
    for (int i = 0; i < 16; i++) is_bytes |= (w[i] > 1u);
    int idx = blockIdx.x * blockDim.x + threadIdx.x;
    if (idx >= n) return;
    float mv;
    if (is_bytes) mv = ((const unsigned char*)mask_raw)[idx] ? 1.f : 0.f;
    else          mv = ((const int*)mask_raw)[idx] ? 1.f : 0.f;
    m[idx] = mv;
}

// ---------------------------------------------------------------------------
// x -> bf16, padded to KPAD stride
// ---------------------------------------------------------------------------
__global__ void xconv_kernel(const float* __restrict__ x,
                             unsigned short* __restrict__ xb, int n) {
    int idx = blockIdx.x * blockDim.x + threadIdx.x;
    int total = n * (KPAD / 2);
    if (idx >= total) return;
    int row = idx / (KPAD / 2);
    int kp  = (idx - row * (KPAD / 2)) * 2;
    ushort2 o;
    if (kp < XS) {
        float2 v = *(const float2*)&x[(size_t)row * XS + kp];
        o.x = f2bf(v.x); o.y = f2bf(v.y);
    } else { o.x = 0; o.y = 0; }
    *(ushort2*)&xb[(size_t)row * KPAD + kp] = o;
}

// ---------------------------------------------------------------------------
// W -> transposed bf16: Wb_t[c][k], c in [0,512)
// ---------------------------------------------------------------------------
__global__ void wconv_kernel(const float* __restrict__ W_iou,
                             const float* __restrict__ W_f,
                             unsigned short* __restrict__ Wb_t) {
    int c = blockIdx.x;
    int k = threadIdx.x;
    float v = 0.f;
    if (k < XS) v = (c < 384) ? W_iou[(size_t)k * 384 + c]
                              : W_f[(size_t)k * 128 + (c - 384)];
    Wb_t[(size_t)c * KPAD + k] = f2bf(v);
}

// ---------------------------------------------------------------------------
// U_f / U_iou -> transposed split-bf16 (hi, lo)
// ---------------------------------------------------------------------------
__global__ void uconv_kernel(const float* __restrict__ U_f,
                             const float* __restrict__ U_iou,
                             unsigned short* __restrict__ Uf_hi,
                             unsigned short* __restrict__ Uf_lo,
                             unsigned short* __restrict__ Uiou_hi,
                             unsigned short* __restrict__ Uiou_lo) {
    int c = blockIdx.x;     // 0..511
    int k = threadIdx.x;    // 0..127
    if (c < 128) {
        float v = U_f[(size_t)k * 128 + c];
        unsigned short hi = f2bf(v);
        Uf_hi[(size_t)c * 128 + k] = hi;
        Uf_lo[(size_t)c * 128 + k] = f2bf(v - bf2f(hi));
    } else {
        int cc = c - 128;
        float v = U_iou[(size_t)k * 384 + cc];
        unsigned short hi = f2bf(v);
        Uiou_hi[(size_t)cc * 128 + k] = hi;
        Uiou_lo[(size_t)cc * 128 + k] = f2bf(v - bf2f(hi));
    }
}

// ---------------------------------------------------------------------------
// Phase A via MFMA (XCD-swizzled); A from pre-converted bf16 xb
// ---------------------------------------------------------------------------
__global__ __launch_bounds__(256) void gemm_in_mfma(
    const unsigned short* __restrict__ xb, const float* __restrict__ m,
    const unsigned short* __restrict__ Wb_t,
    const float* __restrict__ b_iou, const float* __restrict__ b_f,
    float* __restrict__ iou_in, float* __restrict__ f_in, int n)
{
    __shared__ __align__(16) unsigned short Asld[128][72];
    __shared__ __align__(16) unsigned short Bsld[128][72];

    int bid = blockIdx.x;
    int nwg = gridDim.x;
    int q = nwg / NXCD, r = nwg % NXCD;
    int xcd = bid % NXCD, slot = bid / NXCD;
    int nid = (xcd < r) ? (xcd * (q + 1) + slot)
                        : (r * (q + 1) + (xcd - r) * q + slot);
    int bn = nid & 3;
    int bm = nid >> 2;

    int t    = threadIdx.x;
    int lane = t & 63;
    int wid  = t >> 6;
    int wr = wid >> 1, wc = wid & 1;

    int r0 = bm * 128;
    int c0 = bn * 128;

    f32x4 acc[4][4];
#pragma unroll
    for (int i = 0; i < 4; i++)
#pragma unroll
        for (int j = 0; j < 4; j++) acc[i][j] = (f32x4)0.f;

    for (int k0 = 0; k0 < KPAD; k0 += 64) {
        {   // stage A: bf16 xb rows, 2 threads/row x 4 uint4
            int rr = t >> 1;
            int half = t & 1;
            int row = r0 + rr;
            int rowc = row < n ? row : n - 1;
            size_t gb = (size_t)rowc * KPAD + k0 + half * 32;
#pragma unroll
            for (int p = 0; p < 4; p++) {
                uint4 v = *(const uint4*)&xb[gb + p * 8];
                *(uint4*)&Asld[rr][half * 32 + p * 8] = v;
            }
        }
        {   // stage B
            int rr  = t >> 3;
            int kq8 = (t & 7) << 3;
#pragma unroll
            for (int p = 0; p < 4; p++) {
                int col = c0 + rr + p * 32;
                uint4 v = *(const uint4*)&Wb_t[(size_t)col * KPAD + k0 + kq8];
                *(uint4*)&Bsld[rr + p * 32][kq8] = v;
            }
        }
        __syncthreads();

#pragma unroll
        for (int ks = 0; ks < 2; ks++) {
            int kc = ks * 32 + (lane >> 4) * 8;
            short8 af[4], bf[4];
#pragma unroll
            for (int mi = 0; mi < 4; mi++)
                af[mi] = *(const short8*)&Asld[wr * 64 + mi * 16 + (lane & 15)][kc];
#pragma unroll
            for (int ni = 0; ni < 4; ni++)
                bf[ni] = *(const short8*)&Bsld[wc * 64 + ni * 16 + (lane & 15)][kc];
#pragma unroll
            for (int mi = 0; mi < 4; mi++)
#pragma unroll
                for (int ni = 0; ni < 4; ni++)
                    acc[mi][ni] = __builtin_amdgcn_mfma_f32_16x16x32_bf16(
                        af[mi], bf[ni], acc[mi][ni], 0, 0, 0);
        }
        __syncthreads();
    }

    const float* bias;
    float* outp;
    int ldw, colbase;
    if (bn < 3) { bias = b_iou; outp = iou_in; ldw = 384; colbase = bn * 128; }
    else        { bias = b_f;   outp = f_in;   ldw = 128; colbase = 0; }

    float bias_v[4];
#pragma unroll
    for (int ni = 0; ni < 4; ni++)
        bias_v[ni] = bias[colbase + wc * 64 + ni * 16 + (lane & 15)];

#pragma unroll
    for (int mi = 0; mi < 4; mi++) {
#pragma unroll
        for (int j = 0; j < 4; j++) {
            int row = r0 + wr * 64 + mi * 16 + (lane >> 4) * 4 + j;
            if (row >= n) continue;
            float mv = m[row];
#pragma unroll
            for (int ni = 0; ni < 4; ni++) {
                int col = colbase + wc * 64 + ni * 16 + (lane & 15);
                outp[(size_t)row * ldw + col] = mv * (acc[mi][ni][j] + bias_v[ni]);
            }
        }
    }
}

// ---------------------------------------------------------------------------
// Leaves: c = i*u (fp32), h -> single bf16
// ---------------------------------------------------------------------------
__global__ void leaf_kernel(const float* __restrict__ iou_in,
                            unsigned short* __restrict__ h_bf,
                            float* __restrict__ c,
                            int start, int count)
{
    int idx = blockIdx.x * blockDim.x + threadIdx.x;
    int total = count * 32;
    if (idx >= total) return;
    int v = start + (idx >> 5);
    int d = (idx & 31) * 4;
    const float* row = iou_in + (size_t)v * 384;
    float4 iv = *(const float4*)&row[d];
    float4 ov = *(const float4*)&row[128 + d];
    float4 uv = *(const float4*)&row[256 + d];
    float ivv[4] = {iv.x, iv.y, iv.z, iv.w};
    float ovv[4] = {ov.x, ov.y, ov.z, ov.w};
    float uvv[4] = {uv.x, uv.y, uv.z, uv.w};
    float cv[4], hv[4];
#pragma unroll
    for (int e = 0; e < 4; e++) {
        float ig = sigm(ivv[e]), og = sigm(ovv[e]), ug = tanhf(uvv[e]);
        cv[e] = ig * ug;
        hv[e] = og * tanhf(cv[e]);
    }
    *(float4*)&c[(size_t)v * H + d] = make_float4(cv[0], cv[1], cv[2], cv[3]);
    ushort4 hh;
    hh.x = f2bf(hv[0]); hh.y = f2bf(hv[1]);
    hh.z = f2bf(hv[2]); hh.w = f2bf(hv[3]);
    *(ushort4*)&h_bf[(size_t)v * H + d] = hh;
}

// ---------------------------------------------------------------------------
// Fused level kernel: 32 parents (96 children) per block, 128 threads.
// Wave w owns parents 16w..16w+15 and children 48w..48w+47 exclusively.
//   Phase 1: S = h_ch @ U_f (split-U, bf16 A); fc = sigm(S + f_in[par])*c_ch
//            accumulated into LDS fcs via atomicAdd (no cross-wave contention)
//   Segsum:  hs[p] = sum children h, re-rounded bf16, stored into chH[0..31]
//   Phase 2: T = hs @ U_iou (split-U); fused gates -> c (fp32), h (bf16)
// ---------------------------------------------------------------------------
__global__ __launch_bounds__(128) void level_fused(
    const float* __restrict__ iou_in, const float* __restrict__ f_in,
    const unsigned short* __restrict__ Uf_hi, const unsigned short* __restrict__ Uf_lo,
    const unsigned short* __restrict__ Uiou_hi, const unsigned short* __restrict__ Uiou_lo,
    unsigned short* __restrict__ h_bf, float* __restrict__ c,
    int P0, int NP)
{
    __shared__ __align__(16) unsigned short chH[96][136];  // 26.1 KB
    __shared__ float fcs[32][128];                         // 16 KB

    int t = threadIdx.x;
    int C0 = 3 * P0 + 1;
    int pBase = blockIdx.x * 32;
    int chBase = 3 * pBase;
    int M3 = 3 * NP;

    // stage children h (96 rows x 16 uint4-chunks = 1536 chunks, 12/thread)
#pragma unroll
    for (int qq = 0; qq < 12; qq++) {
        int i = t + qq * 128;
        int row = i >> 4, c16 = i & 15;
        int gr = chBase + row;
        int src = (gr < M3) ? (C0 + gr) : C0;
        uint4 v = *(const uint4*)&h_bf[(size_t)src * H + c16 * 8];
        *(uint4*)&chH[row][c16 * 8] = v;
    }
    // zero fcs (4096 floats, 32/thread)
#pragma unroll
    for (int qq = 0; qq < 32; qq++) {
        int i = t + qq * 128;
        fcs[i >> 7][i & 127] = 0.f;
    }
    __syncthreads();

    int lane = t & 63, w = t >> 6;
    int l16 = lane & 15, l4 = lane >> 4;

    // ---- Phase 1: f-gemm, M=48 per wave ----
    f32x4 facc[3][8];
#pragma unroll
    for (int mi = 0; mi < 3; mi++)
#pragma unroll
        for (int nf = 0; nf < 8; nf++) facc[mi][nf] = (f32x4)0.f;

#pragma unroll
    for (int ks = 0; ks < 4; ks++) {
        int kb = ks * 32 + l4 * 8;
        short8 ah[3];
#pragma unroll
        for (int mi = 0; mi < 3; mi++)
            ah[mi] = *(const short8*)&chH[w * 48 + mi * 16 + l16][kb];
#pragma unroll
        for (int nf = 0; nf < 8; nf++) {
            int bc = nf * 16 + l16;
            short8 bh = *(const short8*)&Uf_hi[(size_t)bc * 128 + kb];
            short8 bl = *(const short8*)&Uf_lo[(size_t)bc * 128 + kb];
#pragma unroll
            for (int mi = 0; mi < 3; mi++) {
                facc[mi][nf] = __builtin_amdgcn_mfma_f32_16x16x32_bf16(ah[mi], bh, facc[mi][nf], 0, 0, 0);
                facc[mi][nf] = __builtin_amdgcn_mfma_f32_16x16x32_bf16(ah[mi], bl, facc[mi][nf], 0, 0, 0);
            }
        }
    }
    // epilogue 1: fc into LDS fcs
#pragma unroll
    for (int mi = 0; mi < 3; mi++)
#pragma unroll
        for (int j = 0; j < 4; j++) {
            int lrow = w * 48 + mi * 16 + l4 * 4 + j;   // local child 0..95
            int gr = chBase + lrow;
            if (gr >= M3) continue;
            int gchild = C0 + gr;
            int lpar = lrow / 3;                         // 0..31
            int gpar = P0 + pBase + lpar;
#pragma unroll
            for (int nf = 0; nf < 8; nf++) {
                int col = nf * 16 + l16;
                float s = facc[mi][nf][j] + f_in[(size_t)gpar * H + col];
                float fc = sigm(s) * c[(size_t)gchild * H + col];
                atomicAdd(&fcs[lpar][col], fc);
            }
        }
    __syncthreads();

    // ---- segment-sum h into chH rows 0..31 (bf16 re-round) ----
    short8 sreg[4];
#pragma unroll
    for (int qq = 0; qq < 4; qq++) {
        int i = t + qq * 128;          // 0..511
        int p = i >> 4, c16 = i & 15;
        float hs[8];
#pragma unroll
        for (int e = 0; e < 8; e++) hs[e] = 0.f;
#pragma unroll
        for (int ch = 0; ch < 3; ch++) {
            short8 hv = *(const short8*)&chH[3 * p + ch][c16 * 8];
#pragma unroll
            for (int e = 0; e < 8; e++) hs[e] += bf2f((unsigned short)hv[e]);
        }
#pragma unroll
        for (int e = 0; e < 8; e++) sreg[qq][e] = (short)f2bf(hs[e]);
    }
    __syncthreads();
#pragma unroll
    for (int qq = 0; qq < 4; qq++) {
        int i = t + qq * 128;
        *(short8*)&chH[i >> 4][(i & 15) * 8] = sreg[qq];
    }
    __syncthreads();

    // ---- Phase 2: iou-gemm, M=16 per wave, N=384 ----
    f32x4 acc2[24];
#pragma unroll
    for (int nf = 0; nf < 24; nf++) acc2[nf] = (f32x4)0.f;

#pragma unroll
    for (int ks = 0; ks < 4; ks++) {
        int kb = ks * 32 + l4 * 8;
        short8 ah = *(const short8*)&chH[w * 16 + l16][kb];
#pragma unroll
        for (int nf = 0; nf < 24; nf++) {
            int bc = nf * 16 + l16;
            short8 bh = *(const short8*)&Uiou_hi[(size_t)bc * 128 + kb];
            short8 bl = *(const short8*)&Uiou_lo[(size_t)bc * 128 + kb];
            acc2[nf] = __builtin_amdgcn_mfma_f32_16x16x32_bf16(ah, bh, acc2[nf], 0, 0, 0);
            acc2[nf] = __builtin_amdgcn_mfma_f32_16x16x32_bf16(ah, bl, acc2[nf], 0, 0, 0);
        }
    }
    // epilogue 2: gates
#pragma unroll
    for (int j = 0; j < 4; j++) {
        int lpar = w * 16 + l4 * 4 + j;
        int prow = pBase + lpar;
        if (prow >= NP) continue;
        int v = P0 + prow;
#pragma unroll
        for (int nf8 = 0; nf8 < 8; nf8++) {
            int col = nf8 * 16 + l16;
            size_t iob = (size_t)v * 384 + col;
            float iv = sigm(iou_in[iob]        + acc2[nf8][j]);
            float ov = sigm(iou_in[iob + 128]  + acc2[nf8 + 8][j]);
            float uv = tanhf(iou_in[iob + 256] + acc2[nf8 + 16][j]);
            float cv = iv * uv + fcs[lpar][col];
            float hv = ov * tanhf(cv);
        c[(size_t)v * H + col] = cv;
            h_bf[(size_t)v * H + col] = f2bf(hv);
        }
    }
}

// ---------------------------------------------------------------------------
// Output head: out = h @ W_out + b_out (n x 5)
// ---------------------------------------------------------------------------
__global__ __launch_bounds__(256) void out_kernel(
    const unsigned short* __restrict__ h_bf,
    const float* __restrict__ W_out, const float* __restrict__ b_out,
    float* __restrict__ out, int n)
{
    int wave = (blockIdx.x * blockDim.x + threadIdx.x) >> 6;
    int lane = threadIdx.x & 63;
    if (wave >= n) return;
    size_t hb = (size_t)wave * H;
    float h0 = bf2f(h_bf[hb + lane]);
    float h1 = bf2f(h_bf[hb + lane + 64]);
    float a[NCLS];
#pragma unroll
    for (int j = 0; j < NCLS; j++)
        a[j] = h0 * W_out[lane * NCLS + j] + h1 * W_out[(lane + 64) * NCLS + j];
#pragma unroll
    for (int off = 32; off > 0; off >>= 1)
#pragma unroll
        for (int j = 0; j < NCLS; j++)
            a[j] += __shfl_down(a[j], off, 64);
    if (lane == 0) {
#pragma unroll
        for (int j = 0; j < NCLS; j++)
            out[(size_t)wave * NCLS + j] = a[j] + b_out[j];
    }
}

// ---------------------------------------------------------------------------
extern "C" void kernel_launch(void* const* d_in, const int* in_sizes, int n_in,
                              void* d_out, int out_size, void* d_ws, size_t ws_size,
                              hipStream_t stream) {
    const float* x     = (const float*)d_in[0];
    const void*  mask  = d_in[1];
    const float* W_iou = (const float*)d_in[2];
    const float* b_iou = (const float*)d_in[3];
    const float* W_f   = (const float*)d_in[4];
    const float* b_f   = (const float*)d_in[5];
    const float* U_iou = (const float*)d_in[6];
    const float* U_f   = (const float*)d_in[7];
    const float* W_out = (const float*)d_in[8];
    const float* b_out = (const float*)d_in[9];
    float* out = (float*)d_out;

    int n = in_sizes[1];   // 88573
    size_t nn = (size_t)n;
    size_t mpad = (nn + 7) & ~(size_t)7;

    // layout (f32 units unless noted):
    //  iou_in   nn*384
    //  f_in     nn*128           (pristine through all levels)
    //  mbuf     mpad
    //  cbuf     nn*128  \  alias window: xb (nn*320 u16) + Wb_t (512*320 u16)
    //  h_bf     nn*64   /  (both dead before leaf_kernel writes here)
    //  U splits (u16): Uf_hi/lo 128*128 each, Uiou_hi/lo 384*128 each
    float* ws     = (float*)d_ws;
    float* iou_in = ws;
    float* f_in   = iou_in + nn * 384;
    float* mbuf   = f_in   + nn * 128;
    float* cbuf   = mbuf   + mpad;
    unsigned short* h_bf = (unsigned short*)(cbuf + nn * 128);
    unsigned short* Uf_hi   = h_bf + nn * 128;
    unsigned short* Uf_lo   = Uf_hi + 128 * 128;
    unsigned short* Uiou_hi = Uf_lo + 128 * 128;
    unsigned short* Uiou_lo = Uiou_hi + 384 * 128;
    // aliases (dead after gemm_in):
    unsigned short* xb   = (unsigned short*)cbuf;     // nn*KPAD
    unsigned short* Wb_t = xb + nn * KPAD;            // 512*KPAD

    int pow3[11];
    pow3[0] = 1;
    for (int i = 1; i < 11; i++) pow3[i] = pow3[i - 1] * 3;

    // 0. conversions
    mask_conv_kernel<<<(n + 255) / 256, 256, 0, stream>>>(mask, mbuf, n);
    {
        int total = n * (KPAD / 2);
        xconv_kernel<<<(total + 255) / 256, 256, 0, stream>>>(x, xb, n);
    }
    wconv_kernel<<<512, KPAD, 0, stream>>>(W_iou, W_f, Wb_t);
    uconv_kernel<<<512, 128, 0, stream>>>(U_f, U_iou, Uf_hi, Uf_lo, Uiou_hi, Uiou_lo);

    // 1. input GEMM
    {
        int nwg = 4 * ((n + 127) / 128);
        gemm_in_mfma<<<nwg, 256, 0, stream>>>(xb, mbuf, Wb_t, b_iou, b_f,
                                              iou_in, f_in, n);
    }

    // 2. leaves (level 10)
    {
        int start = (pow3[10] - 1) / 2;   // 29524
        int count = pow3[10];             // 59049
        int total = count * 32;
        leaf_kernel<<<(total + 255) / 256, 256, 0, stream>>>(iou_in, h_bf, cbuf,
                                                             start, count);
    }

    // 3. internal levels 9..0 — ONE fused kernel per level
    for (int lvl = 9; lvl >= 0; --lvl) {
        int NP = pow3[lvl];
        int P0 = (pow3[lvl] - 1) / 2;
        int blocks = (NP + 31) / 32;
        level_fused<<<blocks, 128, 0, stream>>>(iou_in, f_in,
                                                Uf_hi, Uf_lo, Uiou_hi, Uiou_lo,
                                                h_bf, cbuf, P0, NP);
    }

    // 4. output head
    {
        int blocks = (n + 3) / 4;
        out_kernel<<<blocks, 256, 0, stream>>>(h_bf, W_out, b_out, out, n);
    }
}